// Round 1
// baseline (912.666 us; speedup 1.0000x reference)
//
#include <hip/hip_runtime.h>
#include <hip/hip_bf16.h>

#define NN 200000
#define KT 27

typedef __attribute__((ext_vector_type(8))) short bf16x8;
typedef __attribute__((ext_vector_type(4))) float f32x4;
typedef __attribute__((ext_vector_type(4))) unsigned int u32x4;
typedef __attribute__((ext_vector_type(4))) unsigned short u16x4;
typedef __attribute__((ext_vector_type(8))) unsigned short u16x8;

__device__ __forceinline__ unsigned short f2bf(float f) {
  __hip_bfloat16 h = __float2bfloat16(f);
  return __builtin_bit_cast(unsigned short, h);
}
__device__ __forceinline__ float bf2f(unsigned short u) {
  unsigned int x = ((unsigned int)u) << 16;
  return __builtin_bit_cast(float, x);
}
__device__ __forceinline__ float gelu_f(float y) {
  return 0.5f * y * (1.0f + erff(y * 0.7071067811865475f));
}

// ---------------------------------------------------------------------------
// Pack w1 [256][64], w2 [64][256], w3 [27][64][64] (f32) into bf16 MFMA
// B-fragment order: [...kc32-chunk][ntile16][lane64][elem8], where
// k = kc*32 + (lane>>4)*8 + i, n = ntile*16 + (lane&15).
// ---------------------------------------------------------------------------
__global__ __launch_bounds__(256) void k_pack(
    const float* __restrict__ w1, const float* __restrict__ w3,
    const float* __restrict__ w2, unsigned short* __restrict__ w1p,
    unsigned short* __restrict__ w3p, unsigned short* __restrict__ w2p) {
  int tid0 = blockIdx.x * 256 + threadIdx.x;
  int stride = gridDim.x * 256;
  for (int idx = tid0; idx < 16384; idx += stride) {          // w1p: kc<8, t<4
    int i = idx & 7, l = (idx >> 3) & 63, t = (idx >> 9) & 3, kc = idx >> 11;
    int k = kc * 32 + (l >> 4) * 8 + i, n = t * 16 + (l & 15);
    w1p[idx] = f2bf(w1[k * 64 + n]);
  }
  for (int idx = tid0; idx < 16384; idx += stride) {          // w2p: kc<2, t<16
    int i = idx & 7, l = (idx >> 3) & 63, t = (idx >> 9) & 15, kc = idx >> 13;
    int k = kc * 32 + (l >> 4) * 8 + i, n = t * 16 + (l & 15);
    w2p[idx] = f2bf(w2[k * 256 + n]);
  }
  for (int idx = tid0; idx < 110592; idx += stride) {         // w3p: tap<27, kc<2, t<4
    int i = idx & 7, l = (idx >> 3) & 63, t = (idx >> 9) & 3;
    int kc = (idx >> 11) & 1, tap = idx >> 12;
    int kk = kc * 32 + (l >> 4) * 8 + i, d = t * 16 + (l & 15);
    w3p[idx] = f2bf(w3[(tap * 64 + kk) * 64 + d]);
  }
}

// ---------------------------------------------------------------------------
// GEMM1: x1 = data @ w1  (M=200000, K=256, N=64), bf16 MFMA, + column stats.
// Block: 256 rows, 4 waves each 64Mx64N. A staged f32->bf16 into swizzled LDS.
// ---------------------------------------------------------------------------
__global__ __launch_bounds__(256) void k_gemm1(
    const float* __restrict__ data, const unsigned short* __restrict__ w1p,
    unsigned short* __restrict__ x1, float* __restrict__ s_sum,
    float* __restrict__ s_sq) {
  __shared__ unsigned short Abuf[256 * 64];  // 32KB, rows of 128B, XOR-swizzled
  __shared__ unsigned short Bbuf[4096];      // 8KB per 64-wide K chunk
  int tid = threadIdx.x, lane = tid & 63, wave = tid >> 6;
  int rowbase = blockIdx.x * 256;
  f32x4 acc[4][4] = {};

  for (int kcc = 0; kcc < 4; ++kcc) {
    // stage A chunk: 256 rows x 64 cols, f32 -> bf16, swizzled write
#pragma unroll
    for (int p = 0; p < 16; ++p) {
      int r = p * 16 + (tid >> 4);
      int cq = tid & 15;
      int row = rowbase + r;
      f32x4 v = {0.f, 0.f, 0.f, 0.f};
      if (row < NN) v = *(const f32x4*)&data[(size_t)row * 256 + kcc * 64 + cq * 4];
      u16x4 bv;
      bv[0] = f2bf(v[0]); bv[1] = f2bf(v[1]); bv[2] = f2bf(v[2]); bv[3] = f2bf(v[3]);
      *(u16x4*)((char*)Abuf + r * 128 + ((cq * 8) ^ ((r & 7) << 4))) = bv;
    }
    // stage B chunk (8KB, already fragment-ordered)
    {
      const u32x4* src = (const u32x4*)(w1p + kcc * 4096);
      u32x4* dst = (u32x4*)Bbuf;
      dst[tid] = src[tid];
      dst[tid + 256] = src[tid + 256];
    }
    __syncthreads();
#pragma unroll
    for (int half = 0; half < 2; ++half) {
      bf16x8 bfr[4];
#pragma unroll
      for (int t = 0; t < 4; ++t)
        bfr[t] = *(const bf16x8*)&Bbuf[((half * 4 + t) * 64 + lane) * 8];
#pragma unroll
      for (int mt = 0; mt < 4; ++mt) {
        int r = wave * 64 + mt * 16 + (lane & 15);
        bf16x8 a = *(const bf16x8*)((const char*)Abuf + r * 128 +
                     ((half * 64 + ((lane >> 4) * 16)) ^ ((r & 7) << 4)));
#pragma unroll
        for (int t = 0; t < 4; ++t)
          acc[mt][t] = __builtin_amdgcn_mfma_f32_16x16x32_bf16(a, bfr[t], acc[mt][t], 0, 0, 0);
      }
    }
    __syncthreads();
  }

  // epilogue: write x1 (bf16) + per-column sum / sumsq (pad rows are exact 0)
  float cs[4], cq2[4];
#pragma unroll
  for (int t = 0; t < 4; ++t) {
    float s = 0.f, q = 0.f;
#pragma unroll
    for (int mt = 0; mt < 4; ++mt) {
#pragma unroll
      for (int j = 0; j < 4; ++j) {
        float v = acc[mt][t][j];
        s += v; q += v * v;
        int r = rowbase + wave * 64 + mt * 16 + ((lane >> 4) * 4) + j;
        if (r < NN) x1[(size_t)r * 64 + t * 16 + (lane & 15)] = f2bf(v);
      }
    }
    cs[t] = s; cq2[t] = q;
  }
#pragma unroll
  for (int t = 0; t < 4; ++t) {
    cs[t] += __shfl_xor(cs[t], 16);  cs[t] += __shfl_xor(cs[t], 32);
    cq2[t] += __shfl_xor(cq2[t], 16); cq2[t] += __shfl_xor(cq2[t], 32);
  }
  float* red = (float*)Bbuf;  // safe: all waves past last barrier-pair
  if (lane < 16) {
#pragma unroll
    for (int t = 0; t < 4; ++t) {
      red[((wave * 4 + t) * 16 + lane) * 2 + 0] = cs[t];
      red[((wave * 4 + t) * 16 + lane) * 2 + 1] = cq2[t];
    }
  }
  __syncthreads();
  if (tid < 128) {
    int which = tid & 1, col16 = (tid >> 1) & 15, t = tid >> 5;
    float v = 0.f;
#pragma unroll
    for (int w = 0; w < 4; ++w) v += red[((w * 4 + t) * 16 + col16) * 2 + which];
    atomicAdd((which ? s_sq : s_sum) + t * 16 + col16, v);
  }
}

// ---------------------------------------------------------------------------
// BN finalize: a = g*rsqrt(var+eps), c = b - mean*a
// ---------------------------------------------------------------------------
__global__ void k_bn_finalize(const float* __restrict__ sum,
                              const float* __restrict__ sq,
                              const float* __restrict__ g,
                              const float* __restrict__ b,
                              float* __restrict__ a, float* __restrict__ c,
                              int n, float invN) {
  int i = blockIdx.x * blockDim.x + threadIdx.x;
  if (i < n) {
    float m = sum[i] * invN;
    float v = fmaf(-m, m, sq[i] * invN);
    float r = rsqrtf(v + 1e-3f);
    float ai = g[i] * r;
    a[i] = ai;
    c[i] = fmaf(-m, ai, b[i]);
  }
}

// ---------------------------------------------------------------------------
// h = gelu(bn1(x1)) elementwise, bf16 in/out, 8 elems/thread
// ---------------------------------------------------------------------------
__global__ __launch_bounds__(256) void k_bngelu(
    const unsigned short* __restrict__ x1, const float* __restrict__ a,
    const float* __restrict__ c, unsigned short* __restrict__ h) {
  int idx = blockIdx.x * 256 + threadIdx.x;  // exactly NN*64/8 threads
  int cb = (idx & 7) * 8;
  u16x8 v = *(const u16x8*)&x1[(size_t)idx * 8];
  f32x4 a0 = *(const f32x4*)&a[cb], a1 = *(const f32x4*)&a[cb + 4];
  f32x4 c0 = *(const f32x4*)&c[cb], c1 = *(const f32x4*)&c[cb + 4];
  u16x8 o;
#pragma unroll
  for (int j = 0; j < 4; ++j) {
    o[j]     = f2bf(gelu_f(bf2f(v[j])     * a0[j] + c0[j]));
    o[j + 4] = f2bf(gelu_f(bf2f(v[j + 4]) * a1[j] + c1[j]));
  }
  *(u16x8*)&h[(size_t)idx * 8] = o;
}

// ---------------------------------------------------------------------------
// OctreeConv: x2[n,d] = sum_{tap,c} h[neigh[n,tap],c] * w3[tap,c,d]
// Block = 256 nodes, per tap: gather-stage A (swizzled), stage w3p frag tile,
// 2 barriers, 32 MFMA/wave. + column stats (pad rows staged as zeros).
// ---------------------------------------------------------------------------
__global__ __launch_bounds__(256) void k_octconv(
    const unsigned short* __restrict__ h, const int* __restrict__ neigh,
    const unsigned short* __restrict__ w3p, unsigned short* __restrict__ x2,
    float* __restrict__ s_sum, float* __restrict__ s_sq) {
  __shared__ unsigned short Abuf[256 * 64];  // 32KB swizzled gather tile
  __shared__ unsigned short Bbuf[4096];      // 8KB per-tap fragments
  int tid = threadIdx.x, lane = tid & 63, wave = tid >> 6;
  int rowbase = blockIdx.x * 256;
  f32x4 acc[4][4] = {};

  for (int tap = 0; tap < KT; ++tap) {
    // stage B (8KB)
    {
      const u32x4* src = (const u32x4*)(w3p + tap * 4096);
      u32x4* dst = (u32x4*)Bbuf;
      dst[tid] = src[tid];
      dst[tid + 256] = src[tid + 256];
    }
    // gather-stage A: 8 lanes per row x 16B, swizzled LDS write
#pragma unroll
    for (int blk = 0; blk < 8; ++blk) {
      int r = wave * 64 + blk * 8 + (lane >> 3);
      int node = rowbase + r;
      u32x4 v = {0, 0, 0, 0};
      if (node < NN) {
        int idx = neigh[(size_t)node * KT + tap];
        v = *(const u32x4*)&h[(size_t)idx * 64 + (lane & 7) * 8];
      }
      *(u32x4*)((char*)Abuf + r * 128 + (((lane & 7) * 16) ^ ((r & 7) << 4))) = v;
    }
    __syncthreads();
#pragma unroll
    for (int half = 0; half < 2; ++half) {
      bf16x8 bfr[4];
#pragma unroll
      for (int t = 0; t < 4; ++t)
        bfr[t] = *(const bf16x8*)&Bbuf[((half * 4 + t) * 64 + lane) * 8];
#pragma unroll
      for (int mt = 0; mt < 4; ++mt) {
        int r = wave * 64 + mt * 16 + (lane & 15);
        bf16x8 a = *(const bf16x8*)((const char*)Abuf + r * 128 +
                     ((half * 64 + ((lane >> 4) * 16)) ^ ((r & 7) << 4)));
#pragma unroll
        for (int t = 0; t < 4; ++t)
          acc[mt][t] = __builtin_amdgcn_mfma_f32_16x16x32_bf16(a, bfr[t], acc[mt][t], 0, 0, 0);
      }
    }
    __syncthreads();
  }

  // epilogue: write x2 bf16 + stats (identical structure to k_gemm1)
  float cs[4], cq2[4];
#pragma unroll
  for (int t = 0; t < 4; ++t) {
    float s = 0.f, q = 0.f;
#pragma unroll
    for (int mt = 0; mt < 4; ++mt) {
#pragma unroll
      for (int j = 0; j < 4; ++j) {
        float v = acc[mt][t][j];
        s += v; q += v * v;
        int r = rowbase + wave * 64 + mt * 16 + ((lane >> 4) * 4) + j;
        if (r < NN) x2[(size_t)r * 64 + t * 16 + (lane & 15)] = f2bf(v);
      }
    }
    cs[t] = s; cq2[t] = q;
  }
#pragma unroll
  for (int t = 0; t < 4; ++t) {
    cs[t] += __shfl_xor(cs[t], 16);  cs[t] += __shfl_xor(cs[t], 32);
    cq2[t] += __shfl_xor(cq2[t], 16); cq2[t] += __shfl_xor(cq2[t], 32);
  }
  float* red = (float*)Bbuf;
  if (lane < 16) {
#pragma unroll
    for (int t = 0; t < 4; ++t) {
      red[((wave * 4 + t) * 16 + lane) * 2 + 0] = cs[t];
      red[((wave * 4 + t) * 16 + lane) * 2 + 1] = cq2[t];
    }
  }
  __syncthreads();
  if (tid < 128) {
    int which = tid & 1, col16 = (tid >> 1) & 15, t = tid >> 5;
    float v = 0.f;
#pragma unroll
    for (int w = 0; w < 4; ++w) v += red[((w * 4 + t) * 16 + col16) * 2 + which];
    atomicAdd((which ? s_sq : s_sum) + t * 16 + col16, v);
  }
}

// ---------------------------------------------------------------------------
// GEMM2: x3 = gelu(bn2(x2)) @ w2  (M=200000, K=64, N=256) + column stats.
// Block = 128 rows, waves 2Mx2N, wave tile 64Mx128N. BN2+GELU fused into
// the A staging.
// ---------------------------------------------------------------------------
__global__ __launch_bounds__(256) void k_gemm2(
    const unsigned short* __restrict__ x2, const unsigned short* __restrict__ w2p,
    const float* __restrict__ a2, const float* __restrict__ c2,
    unsigned short* __restrict__ x3, float* __restrict__ s_sum,
    float* __restrict__ s_sq) {
  __shared__ unsigned short Abuf[128 * 64];  // 16KB swizzled
  __shared__ unsigned short Bbuf[16384];     // 32KB = full w2p
  int tid = threadIdx.x, lane = tid & 63, wave = tid >> 6;
  int wm = wave >> 1, wn = wave & 1;
  int rowbase = blockIdx.x * 128;
  // stage B (whole w2p)
  {
    const u32x4* src = (const u32x4*)w2p;
    u32x4* dst = (u32x4*)Bbuf;
#pragma unroll
    for (int q = 0; q < 8; ++q) dst[tid + q * 256] = src[tid + q * 256];
  }
  // stage A: x2 -> bn2 -> gelu -> bf16 (pad rows exact 0)
#pragma unroll
  for (int p = 0; p < 4; ++p) {
    int r = p * 32 + (tid >> 3);
    int cq = tid & 7;
    int row = rowbase + r;
    u16x8 ov = {0, 0, 0, 0, 0, 0, 0, 0};
    if (row < NN) {
      u16x8 v = *(const u16x8*)&x2[(size_t)row * 64 + cq * 8];
#pragma unroll
      for (int j = 0; j < 8; ++j) {
        int col = cq * 8 + j;
        ov[j] = f2bf(gelu_f(bf2f(v[j]) * a2[col] + c2[col]));
      }
    }
    *(u16x8*)((char*)Abuf + r * 128 + ((cq * 16) ^ ((r & 7) << 4))) = ov;
  }
  f32x4 acc[4][8] = {};
  __syncthreads();
#pragma unroll
  for (int half = 0; half < 2; ++half) {
    bf16x8 a[4];
#pragma unroll
    for (int mt = 0; mt < 4; ++mt) {
      int r = wm * 64 + mt * 16 + (lane & 15);
      a[mt] = *(const bf16x8*)((const char*)Abuf + r * 128 +
                ((half * 64 + ((lane >> 4) * 16)) ^ ((r & 7) << 4)));
    }
#pragma unroll
    for (int t = 0; t < 8; ++t) {
      bf16x8 b = *(const bf16x8*)&Bbuf[((half * 16 + wn * 8 + t) * 64 + lane) * 8];
#pragma unroll
      for (int mt = 0; mt < 4; ++mt)
        acc[mt][t] = __builtin_amdgcn_mfma_f32_16x16x32_bf16(a[mt], b, acc[mt][t], 0, 0, 0);
    }
  }
  // epilogue: write x3 bf16 + stats over 256 cols
  float cs[8], cq2[8];
#pragma unroll
  for (int t = 0; t < 8; ++t) {
    float s = 0.f, q = 0.f;
#pragma unroll
    for (int mt = 0; mt < 4; ++mt) {
#pragma unroll
      for (int j = 0; j < 4; ++j) {
        float v = acc[mt][t][j];
        s += v; q += v * v;
        int r = rowbase + wm * 64 + mt * 16 + ((lane >> 4) * 4) + j;
        if (r < NN)
          x3[(size_t)r * 256 + wn * 128 + t * 16 + (lane & 15)] = f2bf(v);
      }
    }
    cs[t] = s; cq2[t] = q;
  }
#pragma unroll
  for (int t = 0; t < 8; ++t) {
    cs[t] += __shfl_xor(cs[t], 16);  cs[t] += __shfl_xor(cs[t], 32);
    cq2[t] += __shfl_xor(cq2[t], 16); cq2[t] += __shfl_xor(cq2[t], 32);
  }
  __syncthreads();  // all waves done reading Bbuf
  float* red = (float*)Bbuf;  // 1024 floats
  if (lane < 16) {
#pragma unroll
    for (int t = 0; t < 8; ++t) {
      red[((wave * 8 + t) * 16 + lane) * 2 + 0] = cs[t];
      red[((wave * 8 + t) * 16 + lane) * 2 + 1] = cq2[t];
    }
  }
  __syncthreads();
#pragma unroll
  for (int e = tid; e < 512; e += 256) {
    int which = e & 1;
    int colg = e >> 1;  // 0..255
    int wn2 = colg >> 7, t = (colg >> 4) & 7, c16 = colg & 15;
    float v = 0.f;
#pragma unroll
    for (int wm2 = 0; wm2 < 2; ++wm2) {
      int w = wm2 * 2 + wn2;
      v += red[((w * 8 + t) * 16 + c16) * 2 + which];
    }
    atomicAdd((which ? s_sq : s_sum) + colg, v);
  }
}

// ---------------------------------------------------------------------------
// out = elu(bn3(x3) + data), 8 elems/thread
// ---------------------------------------------------------------------------
__global__ __launch_bounds__(256) void k_finish(
    const unsigned short* __restrict__ x3, const float* __restrict__ data,
    const float* __restrict__ a3, const float* __restrict__ c3,
    float* __restrict__ out) {
  size_t idx = (size_t)blockIdx.x * 256 + threadIdx.x;  // exactly NN*256/8
  int cb = (int)(idx & 31) * 8;
  u16x8 v = *(const u16x8*)&x3[idx * 8];
  f32x4 a0 = *(const f32x4*)&a3[cb], a1 = *(const f32x4*)&a3[cb + 4];
  f32x4 c0 = *(const f32x4*)&c3[cb], c1 = *(const f32x4*)&c3[cb + 4];
  f32x4 d0 = *(const f32x4*)&data[idx * 8], d1 = *(const f32x4*)&data[idx * 8 + 4];
  f32x4 o0, o1;
#pragma unroll
  for (int j = 0; j < 4; ++j) {
    float y0 = bf2f(v[j]) * a0[j] + c0[j] + d0[j];
    float y1 = bf2f(v[j + 4]) * a1[j] + c1[j] + d1[j];
    o0[j] = y0 > 0.f ? y0 : expm1f(y0);
    o1[j] = y1 > 0.f ? y1 : expm1f(y1);
  }
  *(f32x4*)&out[idx * 8] = o0;
  *(f32x4*)&out[idx * 8 + 4] = o1;
}

// ---------------------------------------------------------------------------
// Host launcher. ws layout (bytes):
//   0        w1p (32KB) | 32768 w2p (32KB) | 65536 w3p (216KB)
//   286720   stats: [s1 64|s1q 64|a1 64|c1 64| s2.. | s3 256|s3q 256|a3 256|c3 256]
//   1MiB     x1 / x2 bf16 (25.6MB, x2 reuses x1 after h is built)
//   28MiB    h bf16 (25.6MB) / x3 bf16 (102.4MB, reuses h region after K4)
// peak ws use ~126MB.
// ---------------------------------------------------------------------------
extern "C" void kernel_launch(void* const* d_in, const int* in_sizes, int n_in,
                              void* d_out, int out_size, void* d_ws, size_t ws_size,
                              hipStream_t stream) {
  const float* data = (const float*)d_in[0];
  const int* neigh = (const int*)d_in[1];
  const float* w1 = (const float*)d_in[2];
  const float* g1 = (const float*)d_in[3];
  const float* b1 = (const float*)d_in[4];
  const float* w3 = (const float*)d_in[5];
  const float* g3 = (const float*)d_in[6];
  const float* b3 = (const float*)d_in[7];
  const float* w2 = (const float*)d_in[8];
  const float* g2 = (const float*)d_in[9];
  const float* b2 = (const float*)d_in[10];
  float* out = (float*)d_out;
  char* ws = (char*)d_ws;

  unsigned short* w1p = (unsigned short*)(ws);
  unsigned short* w2p = (unsigned short*)(ws + 32768);
  unsigned short* w3p = (unsigned short*)(ws + 65536);
  float* S = (float*)(ws + 286720);
  unsigned short* x1 = (unsigned short*)(ws + (1 << 20));
  unsigned short* x2 = x1;                                   // reuse after K3
  unsigned short* hb = (unsigned short*)(ws + (size_t)(28 << 20));
  unsigned short* x3 = hb;                                   // reuse after K4

  const float invN = 1.0f / (float)NN;

  hipMemsetAsync(S, 0, 6144, stream);
  k_pack<<<64, 256, 0, stream>>>(w1, w3, w2, w1p, w3p, w2p);
  k_gemm1<<<782, 256, 0, stream>>>(data, w1p, x1, S + 0, S + 64);
  k_bn_finalize<<<1, 256, 0, stream>>>(S + 0, S + 64, g1, b1, S + 128, S + 192, 64, invN);
  k_bngelu<<<6250, 256, 0, stream>>>(x1, S + 128, S + 192, hb);
  k_octconv<<<782, 256, 0, stream>>>(hb, neigh, w3p, x2, S + 256, S + 320);
  k_bn_finalize<<<1, 256, 0, stream>>>(S + 256, S + 320, g3, b3, S + 384, S + 448, 64, invN);
  k_gemm2<<<1563, 256, 0, stream>>>(x2, w2p, S + 384, S + 448, x3, S + 512, S + 768);
  k_bn_finalize<<<1, 256, 0, stream>>>(S + 512, S + 768, g2, b2, S + 1024, S + 1280, 256, invN);
  k_finish<<<25000, 256, 0, stream>>>(x3, data, S + 1024, S + 1280, out);
}